// Round 18
// baseline (128.229 us; speedup 1.0000x reference)
//
#include <hip/hip_runtime.h>
#include <hip/hip_cooperative_groups.h>
#include <hip/hip_bf16.h>
#include <math.h>

namespace cg = cooperative_groups;

// Problem sizes
#define Bn 4096
#define Dn 128
#define Cn 1000
#define Qn 65536

typedef __attribute__((ext_vector_type(8))) short short8v;  // bf16x8 MFMA frag
typedef __attribute__((ext_vector_type(4))) float f32x4;    // fp32x4 acc frag
typedef __attribute__((ext_vector_type(4))) float f4v;      // native float4
typedef unsigned short u16;

__device__ inline float waveAllMaxF(float v) {
    for (int o = 32; o; o >>= 1) v = fmaxf(v, __shfl_xor(v, o));
    return v;
}
__device__ inline float waveAllSumF(float v) {
    for (int o = 32; o; o >>= 1) v += __shfl_xor(v, o);
    return v;
}
__device__ inline float waveSumF(float v) {
    for (int o = 32; o; o >>= 1) v += __shfl_down(v, o);
    return v;
}
__device__ inline short f2bf(float x) {
    union { __hip_bfloat16 h; short s; } u;
    u.h = __float2bfloat16(x);
    return u.s;
}

// Virtual-block layout
//   Phase A (2816 vb): [0,256) gemm | [256,512) cls(16 rows) | [512,768) feat | [768,2816) queue
//   Phase B (1045 vb): [0,500) proto(2 classes) | [500,1045) tail
// PHASE: 0 = A only (normal launch), 1 = B only (normal launch), 2 = A+grid.sync+B (cooperative)
template <int PHASE>
__global__ __launch_bounds__(256) void k_coop(
    const float* __restrict__ logits, const float* __restrict__ plabel,
    const float* __restrict__ q, const float* __restrict__ proto,
    const float* __restrict__ kk, const float* __restrict__ queue,
    const float* __restrict__ qps, const int* __restrict__ ptrp,
    float* __restrict__ out_cls, float* __restrict__ outC,
    float* __restrict__ out_feat, float* __restrict__ out_lab,
    float* __restrict__ outp, float* __restrict__ out_queue,
    float* __restrict__ out_qps, float* __restrict__ out_ptr,
    int* __restrict__ lbl)
{
    __shared__ __align__(16) char smem[16448];
    int t = threadIdx.x;

    if (PHASE != 1) {
        for (int vb = blockIdx.x; vb < 2816; vb += gridDim.x) {
            if (vb < 256) {
                // ---- gemm: 16 rows x 1024 cols, in-register bf16 cvt ----
                float (*red)[4] = (float (*)[4])smem;
                int lane = t & 63, w = t >> 6;
                int la = lane & 15, lk = lane >> 4;
                int row0 = vb * 16;

                f32x4 acc[16];
#pragma unroll
                for (int j = 0; j < 16; ++j) acc[j] = (f32x4){0.f, 0.f, 0.f, 0.f};

                const float* A0 = q + (long long)(row0 + la) * Dn;
#pragma unroll
                for (int kc = 0; kc < Dn; kc += 32) {
                    short8v a;
                    {
                        f4v f0 = *(const f4v*)(A0 + kc + lk * 8);
                        f4v f1 = *(const f4v*)(A0 + kc + lk * 8 + 4);
                        a[0] = f2bf(f0.x); a[1] = f2bf(f0.y); a[2] = f2bf(f0.z); a[3] = f2bf(f0.w);
                        a[4] = f2bf(f1.x); a[5] = f2bf(f1.y); a[6] = f2bf(f1.z); a[7] = f2bf(f1.w);
                    }
#pragma unroll
                    for (int j = 0; j < 16; ++j) {
                        int prow = w * 256 + j * 16 + la;
                        short8v b = {0, 0, 0, 0, 0, 0, 0, 0};
                        if (prow < Cn) {
                            const float* Bp0 = proto + (long long)prow * Dn + kc + lk * 8;
                            f4v f0 = *(const f4v*)Bp0;
                            f4v f1 = *(const f4v*)(Bp0 + 4);
                            b[0] = f2bf(f0.x); b[1] = f2bf(f0.y); b[2] = f2bf(f0.z); b[3] = f2bf(f0.w);
                            b[4] = f2bf(f1.x); b[5] = f2bf(f1.y); b[6] = f2bf(f1.z); b[7] = f2bf(f1.w);
                        }
                        acc[j] = __builtin_amdgcn_mfma_f32_16x16x32_bf16(a, b, acc[j], 0, 0, 0);
                    }
                }

                float m[4];
#pragma unroll
                for (int rg = 0; rg < 4; ++rg) {
                    float v = -INFINITY;
#pragma unroll
                    for (int j = 0; j < 16; ++j) {
                        int col = w * 256 + j * 16 + la;
                        if (col < Cn) v = fmaxf(v, acc[j][rg]);
                    }
#pragma unroll
                    for (int o = 1; o < 16; o <<= 1) v = fmaxf(v, __shfl_xor(v, o));
                    m[rg] = v;
                }
                if (la == 0) {
#pragma unroll
                    for (int rg = 0; rg < 4; ++rg) red[lk * 4 + rg][w] = m[rg];
                }
                __syncthreads();
#pragma unroll
                for (int rg = 0; rg < 4; ++rg) {
                    int r = lk * 4 + rg;
                    m[rg] = fmaxf(fmaxf(red[r][0], red[r][1]), fmaxf(red[r][2], red[r][3]));
                }
                __syncthreads();

                float s[4];
#pragma unroll
                for (int rg = 0; rg < 4; ++rg) {
                    float v = 0.f;
#pragma unroll
                    for (int j = 0; j < 16; ++j) {
                        int col = w * 256 + j * 16 + la;
                        float e = (col < Cn) ? expf(acc[j][rg] - m[rg]) : 0.f;
                        acc[j][rg] = e;
                        v += e;
                    }
#pragma unroll
                    for (int o = 1; o < 16; o <<= 1) v += __shfl_xor(v, o);
                    s[rg] = v;
                }
                if (la == 0) {
#pragma unroll
                    for (int rg = 0; rg < 4; ++rg) red[lk * 4 + rg][w] = s[rg];
                }
                __syncthreads();
#pragma unroll
                for (int rg = 0; rg < 4; ++rg) {
                    int r = lk * 4 + rg;
                    s[rg] = 1.f / (red[r][0] + red[r][1] + red[r][2] + red[r][3]);
                }

#pragma unroll
                for (int j = 0; j < 16; ++j) {
                    int col = w * 256 + j * 16 + la;
                    if (col < Cn) {
                        int rowb = row0 + lk * 4;
#pragma unroll
                        for (int rg = 0; rg < 4; ++rg)
                            outC[(long long)(rowb + rg) * Cn + col] = acc[j][rg] * s[rg];
                    }
                }
                __syncthreads();   // smem reused by later roles of this block
            } else if (vb < 512) {
                // ---- cls: 16 rows; each wave 4 rows sequentially ----
                int cb = vb - 256;
                int lane = t & 63, wid = t >> 6;
                for (int it = 0; it < 4; ++it) {
                    int row = cb * 16 + wid * 4 + it;
                    const float* x  = logits + (long long)row * Cn;
                    const float* pl = plabel + (long long)row * Cn;

                    f4v lv[4], pv[4];
#pragma unroll
                    for (int j = 0; j < 4; ++j) {
                        int f4i = lane + j * 64;
                        if (f4i < 250) {
                            lv[j] = *(const f4v*)(x + f4i * 4);
                            pv[j] = *(const f4v*)(pl + f4i * 4);
                        } else {
                            lv[j] = (f4v){-INFINITY, -INFINITY, -INFINITY, -INFINITY};
                            pv[j] = (f4v){0.f, 0.f, 0.f, 0.f};
                        }
                    }

                    float mx = -INFINITY;
#pragma unroll
                    for (int j = 0; j < 4; ++j)
                        mx = fmaxf(mx, fmaxf(fmaxf(lv[j].x, lv[j].y), fmaxf(lv[j].z, lv[j].w)));
                    mx = waveAllMaxF(mx);

                    float ssum = 0.f;
#pragma unroll
                    for (int j = 0; j < 4; ++j) {
                        lv[j].x = expf(lv[j].x - mx);
                        lv[j].y = expf(lv[j].y - mx);
                        lv[j].z = expf(lv[j].z - mx);
                        lv[j].w = expf(lv[j].w - mx);
                        ssum += lv[j].x + lv[j].y + lv[j].z + lv[j].w;
                    }
                    ssum = waveAllSumF(ssum);
                    float inv = 1.f / ssum;

                    float bv = -INFINITY; int bi = Cn;
#pragma unroll
                    for (int j = 0; j < 4; ++j) {
                        int f4i = lane + j * 64;
                        if (f4i < 250) {
                            f4v o4 = {lv[j].x * inv, lv[j].y * inv, lv[j].z * inv, lv[j].w * inv};
                            *((f4v*)(out_cls + (long long)row * Cn) + f4i) = o4;
                            float pr[4] = {o4.x * pv[j].x, o4.y * pv[j].y, o4.z * pv[j].z, o4.w * pv[j].w};
#pragma unroll
                            for (int jj = 0; jj < 4; ++jj) {
                                if (pr[jj] > bv) { bv = pr[jj]; bi = f4i * 4 + jj; }
                            }
                        }
                    }
                    for (int o = 32; o; o >>= 1) {
                        float ov = __shfl_xor(bv, o);
                        int   oi = __shfl_xor(bi, o);
                        if (ov > bv || (ov == bv && oi < bi)) { bv = ov; bi = oi; }
                    }
                    if (lane == 0) lbl[row] = bi;
                }
            } else if (vb < 768) {
                // ---- feat q|k tile: 4096 floats, one source ----
                int fb = vb - 512;
                const float* src = (fb < 128) ? q : kk;
                long long sb = (long long)(fb & 127) * 4096;
                long long db = (long long)fb * 4096;
                f4v v[4];
#pragma unroll
                for (int u = 0; u < 4; ++u)
                    v[u] = *(const f4v*)(src + sb + (u * 256 + t) * 4);
#pragma unroll
                for (int u = 0; u < 4; ++u)
                    *(f4v*)(out_feat + db + (u * 256 + t) * 4) = v[u];
            } else {
                // ---- queue tile: 4096 floats; loads first, then stores ----
                int cb = vb - 768;
                int p = *ptrp;
                int pc = p < 0 ? 0 : (p > Qn - Bn ? Qn - Bn : p);
                long long base = (long long)cb * 4096;
                const long long FB = 2LL * Bn * Dn;      // 1048576
                f4v v[4];
#pragma unroll
                for (int u = 0; u < 4; ++u)
                    v[u] = *(const f4v*)(queue + base + (u * 256 + t) * 4);
#pragma unroll
                for (int u = 0; u < 4; ++u)
                    *(f4v*)(out_feat + FB + base + (u * 256 + t) * 4) = v[u];
#pragma unroll
                for (int u = 0; u < 4; ++u) {
                    long long foff = base + (u * 256 + t) * 4;
                    int row = (int)(foff >> 7);
                    unsigned rr = (unsigned)(row - pc);
                    f4v wv = v[u];
                    if (rr < (unsigned)Bn) wv = *(const f4v*)(kk + (long long)rr * Dn + (foff & 127));
                    *(f4v*)(out_queue + foff) = wv;
                }
            }
        }
    }

    if (PHASE == 2) {
        cg::this_grid().sync();
    }

    if (PHASE != 0) {
        for (int vb = blockIdx.x; vb < 1045; vb += gridDim.x) {
            if (vb < 500) {
                // ---- proto: 2 classes/block, ushort-staged (16.4 KB) ----
                u16* slab = (u16*)smem;                        // [4096]  8 KB
                u16* list0 = (u16*)(smem + 8192);              // [2048]  4 KB
                u16* list1 = (u16*)(smem + 12288);             // [2048]  4 KB
                int* nm = (int*)(smem + 16384);                // [2]
                float* shh = (float*)(smem + 16392);           // [4]

                int h = t >> 7, tt = t & 127;
                int c = vb * 2 + h;                            // < 1000 always

                __syncthreads();                               // guard smem reuse across vb
#pragma unroll
                for (int u = 0; u < 4; ++u) {
                    int4 v = ((const int4*)lbl)[u * 256 + t];
                    int base = (u * 256 + t) * 4;
                    slab[base + 0] = (u16)v.x; slab[base + 1] = (u16)v.y;
                    slab[base + 2] = (u16)v.z; slab[base + 3] = (u16)v.w;
                }
                if (t == 0)   nm[0] = 0;
                if (t == 128) nm[1] = 0;
                __syncthreads();

                int wv2 = t >> 6;
                if ((wv2 & 1) == 0) {          // waves 0 and 2 scan for their half's class
                    int hh = wv2 >> 1;
                    int ln = t & 63;
                    u16 cc = (u16)(vb * 2 + hh);
                    u16* lst = hh ? list1 : list0;
                    int n = 0;
                    for (int jj = 0; jj < Bn / 64; ++jj) {
                        unsigned long long mask = __ballot(slab[jj * 64 + ln] == cc);
                        if (ln == 0) {
                            while (mask && n < 2048) {
                                int b = __builtin_ctzll(mask);
                                lst[n++] = (u16)(jj * 64 + b);
                                mask &= mask - 1;
                            }
                        }
                    }
                    if (ln == 0) nm[hh] = n;
                }
                __syncthreads();

                int n = nm[h];
                u16* lst = h ? list1 : list0;
                float acc = proto[(long long)c * Dn + tt];
                for (int mi = 0; mi < n; ++mi)
                    acc = 0.99f * acc + 0.01f * q[(long long)lst[mi] * Dn + tt];

                float ss = waveSumF(acc * acc);
                if ((t & 63) == 0) shh[t >> 6] = ss;
                __syncthreads();
                float nn = sqrtf(shh[h * 2] + shh[h * 2 + 1]);
                outp[(long long)c * Dn + tt] = acc / fmaxf(nn, 1e-12f);
            } else {
                // ---- labels / queue_pseudo / ptr tail ----
                int gid = (vb - 500) * 256 + t;
                const int NL = 2 * Bn + Qn;   // 73728
                int p = *ptrp;
                int pc = p < 0 ? 0 : (p > Qn - Bn ? Qn - Bn : p);
                if (gid < NL) {
                    float v;
                    if (gid < Bn)          v = (float)lbl[gid];
                    else if (gid < 2 * Bn) v = (float)lbl[gid - Bn];
                    else                   v = qps[gid - 2 * Bn];
                    out_lab[gid] = v;
                }
                int j = gid - NL;
                if (j >= 0 && j < Qn) {
                    unsigned rr = (unsigned)(j - pc);
                    out_qps[j] = (rr < (unsigned)Bn) ? (float)lbl[rr] : qps[j];
                }
                if (gid == NL + Qn) out_ptr[0] = (float)((p + Bn) % Qn);
            }
        }
    }
}

// ---------------- host ----------------
extern "C" void kernel_launch(void* const* d_in, const int* in_sizes, int n_in,
                              void* d_out, int out_size, void* d_ws, size_t ws_size,
                              hipStream_t stream)
{
    const float* q     = (const float*)d_in[0];
    const float* kk    = (const float*)d_in[1];
    const float* cl    = (const float*)d_in[2];
    const float* plab  = (const float*)d_in[3];
    const float* proto = (const float*)d_in[4];
    const float* queue = (const float*)d_in[5];
    const float* qps   = (const float*)d_in[6];
    const int*   ptrp  = (const int*)d_in[7];

    float* out = (float*)d_out;
    // output layout (flat float offsets, return order)
    const long long O_CLU  = 4096000;     // cluster_out
    const long long O_FEAT = 8192000;     // cont_features
    const long long O_LAB  = 17629184;    // cont_labels
    const long long O_PROT = 17702912;    // new_prototypes
    const long long O_QUE  = 17830912;    // new_queue
    const long long O_QPS  = 26219520;    // new_queue_pseudo
    const long long O_PTR  = 26285056;    // new_ptr

    char* ws = (char*)d_ws;
    int* lbl = (int*)(ws + 0);            // [4096]

    const float* a_out_cls  = out;
    float* p_out_cls  = out;
    float* p_outC     = out + O_CLU;
    float* p_out_feat = out + O_FEAT;
    float* p_out_lab  = out + O_LAB;
    float* p_outp     = out + O_PROT;
    float* p_out_que  = out + O_QUE;
    float* p_out_qps  = out + O_QPS;
    float* p_out_ptr  = out + O_PTR;
    (void)a_out_cls;

    void* args[17] = {
        (void*)&cl, (void*)&plab, (void*)&q, (void*)&proto,
        (void*)&kk, (void*)&queue, (void*)&qps, (void*)&ptrp,
        (void*)&p_out_cls, (void*)&p_outC, (void*)&p_out_feat, (void*)&p_out_lab,
        (void*)&p_outp, (void*)&p_out_que, (void*)&p_out_qps, (void*)&p_out_ptr,
        (void*)&lbl
    };

    int occ = 0;
    hipError_t e = hipOccupancyMaxActiveBlocksPerMultiprocessor(&occ, k_coop<2>, 256, 0);
    bool coop_ok = (e == hipSuccess && occ > 0);
    if (coop_ok) {
        long long grid = (long long)occ * 256;      // 256 CUs on MI355X
        if (grid > 2816) grid = 2816;
        hipError_t e2 = hipLaunchCooperativeKernel(k_coop<2>, dim3((unsigned)grid),
                                                   dim3(256), args, 0, stream);
        if (e2 != hipSuccess) coop_ok = false;
    }
    if (!coop_ok) {
        // fallback: same code as two ordinary launches (R11-class structure)
        k_coop<0><<<2816, 256, 0, stream>>>(cl, plab, q, proto, kk, queue, qps, ptrp,
                                            p_out_cls, p_outC, p_out_feat, p_out_lab,
                                            p_outp, p_out_que, p_out_qps, p_out_ptr, lbl);
        k_coop<1><<<1045, 256, 0, stream>>>(cl, plab, q, proto, kk, queue, qps, ptrp,
                                            p_out_cls, p_outC, p_out_feat, p_out_lab,
                                            p_outp, p_out_que, p_out_qps, p_out_ptr, lbl);
    }
}

// Round 19
// 54.575 us; speedup vs baseline: 2.3496x; 2.3496x over previous
//
#include <hip/hip_runtime.h>
#include <hip/hip_bf16.h>
#include <math.h>

// Problem sizes
#define Bn 4096
#define Dn 128
#define Cn 1000
#define Qn 65536

typedef __attribute__((ext_vector_type(8))) short short8v;  // bf16x8 MFMA frag
typedef __attribute__((ext_vector_type(4))) short short4v;  // bf16x4 store
typedef __attribute__((ext_vector_type(4))) float f32x4;    // fp32x4 acc frag
typedef __attribute__((ext_vector_type(4))) float f4v;      // native float4
typedef unsigned short u16;

__device__ inline float waveAllMaxF(float v) {
    for (int o = 32; o; o >>= 1) v = fmaxf(v, __shfl_xor(v, o));
    return v;
}
__device__ inline float waveAllSumF(float v) {
    for (int o = 32; o; o >>= 1) v += __shfl_xor(v, o);
    return v;
}
__device__ inline float waveSumF(float v) {
    for (int o = 32; o; o >>= 1) v += __shfl_down(v, o);
    return v;
}
__device__ inline short f2bf(float x) {
    union { __hip_bfloat16 h; short s; } u;
    u.h = __float2bfloat16(x);
    return u.s;
}
__device__ inline f4v ntl(const f4v* p) { return __builtin_nontemporal_load(p); }
__device__ inline void nts(f4v v, f4v* p) { __builtin_nontemporal_store(v, p); }

// ================= K1: cls only (R14 + NT streaming hints) =================
// 1024 blocks: 4 rows each, one wave per row; logits AND plabel loads issued
// together up front (8 outstanding 16B loads/lane) + bf16-convert fold.
__global__ __launch_bounds__(256) void k_cls(
    const float* __restrict__ logits, const float* __restrict__ plabel,
    const float* __restrict__ q, const float* __restrict__ proto,
    float* __restrict__ out_cls, int* __restrict__ labels,
    __hip_bfloat16* __restrict__ qb, __hip_bfloat16* __restrict__ pb)
{
    int g = blockIdx.x, t = threadIdx.x;

    if (t < 160) {
        int idx4 = g * 160 + t;
        if (idx4 < 131072) {                      // q: 524288/4
            f4v v = *(const f4v*)(q + (long long)idx4 * 4);
            short4v o = {f2bf(v.x), f2bf(v.y), f2bf(v.z), f2bf(v.w)};
            *(short4v*)((short*)qb + (long long)idx4 * 4) = o;
        } else {
            int j4 = idx4 - 131072;               // proto: 32768 float4 slots (padded)
            short4v o = {0, 0, 0, 0};
            if (j4 < 32000) {
                f4v v = *(const f4v*)(proto + (long long)j4 * 4);
                o = (short4v){f2bf(v.x), f2bf(v.y), f2bf(v.z), f2bf(v.w)};
            }
            *(short4v*)((short*)pb + (long long)j4 * 4) = o;
        }
    }

    int lane = t & 63, wid = t >> 6;
    int row = g * 4 + wid;
    const float* x  = logits + (long long)row * Cn;
    const float* pl = plabel + (long long)row * Cn;

    f4v lv[4], pv[4];
#pragma unroll
    for (int j = 0; j < 4; ++j) {                 // issue ALL loads up front (MLP=8)
        int f4i = lane + j * 64;
        if (f4i < 250) {
            lv[j] = ntl((const f4v*)(x + f4i * 4));
            pv[j] = ntl((const f4v*)(pl + f4i * 4));
        } else {
            lv[j] = (f4v){-INFINITY, -INFINITY, -INFINITY, -INFINITY};
            pv[j] = (f4v){0.f, 0.f, 0.f, 0.f};
        }
    }

    float mx = -INFINITY;
#pragma unroll
    for (int j = 0; j < 4; ++j)
        mx = fmaxf(mx, fmaxf(fmaxf(lv[j].x, lv[j].y), fmaxf(lv[j].z, lv[j].w)));
    mx = waveAllMaxF(mx);

    float vv[16];
    float ssum = 0.f;
#pragma unroll
    for (int j = 0; j < 4; ++j) {
        vv[j * 4 + 0] = expf(lv[j].x - mx);
        vv[j * 4 + 1] = expf(lv[j].y - mx);
        vv[j * 4 + 2] = expf(lv[j].z - mx);
        vv[j * 4 + 3] = expf(lv[j].w - mx);
        ssum += vv[j * 4 + 0] + vv[j * 4 + 1] + vv[j * 4 + 2] + vv[j * 4 + 3];
    }
    ssum = waveAllSumF(ssum);
    float inv = 1.f / ssum;

    float bv = -INFINITY; int bi = Cn;
#pragma unroll
    for (int j = 0; j < 4; ++j) {
        int f4i = lane + j * 64;
        if (f4i < 250) {
            float o0 = vv[j * 4 + 0] * inv, o1 = vv[j * 4 + 1] * inv;
            float o2 = vv[j * 4 + 2] * inv, o3 = vv[j * 4 + 3] * inv;
            nts((f4v){o0, o1, o2, o3}, (f4v*)(out_cls + (long long)row * Cn) + f4i);
            float pr[4] = {o0 * pv[j].x, o1 * pv[j].y, o2 * pv[j].z, o3 * pv[j].w};
#pragma unroll
            for (int jj = 0; jj < 4; ++jj) {
                if (pr[jj] > bv) { bv = pr[jj]; bi = f4i * 4 + jj; }
            }
        }
    }
    for (int o = 32; o; o >>= 1) {
        float ov = __shfl_xor(bv, o);
        int   oi = __shfl_xor(bi, o);
        if (ov > bv || (ov == bv && oi < bi)) { bv = ov; bi = oi; }
    }
    if (lane == 0) labels[row] = bi;
}

// ================= K2: compute-first union (R14 structure + NT streaming hints) =================
// 3605 blocks:
//   bid <  256 : cluster GEMM + row softmax (16 rows/block, bf16 qb/pb)
//   bid <  756 : prototype EMA + L2 norm (ushort-staged, 16.4 KB LDS, 2 classes/block)
//   bid < 1301 : cont_labels / new_queue_pseudo / new_ptr tail (545 blocks)
//   bid < 1557 : feat q|k tile (256, branch-free, MLP-4)
//   else       : queue tile -> out_feat + out_queue (2048, loads-first MLP-4)
__global__ __launch_bounds__(256) void k_rest(
    const __hip_bfloat16* __restrict__ qb, const __hip_bfloat16* __restrict__ pbuf,
    const float* __restrict__ proto, const float* __restrict__ q,
    const float* __restrict__ kk, const float* __restrict__ queue,
    const int* __restrict__ lbl, const float* __restrict__ qps,
    const int* __restrict__ ptrp,
    float* __restrict__ outC, float* __restrict__ outp,
    float* __restrict__ out_lab, float* __restrict__ out_qps,
    float* __restrict__ out_ptr,
    float* __restrict__ out_feat, float* __restrict__ out_queue)
{
    __shared__ __align__(16) char smem[16448];
    int bid = blockIdx.x, t = threadIdx.x;

    if (bid < 256) {
        // ---- GEMM + softmax (R11 verbatim; NT on outC stores) ----
        float (*red)[4] = (float (*)[4])smem;   // [16][4]
        int lane = t & 63, w = t >> 6;
        int la = lane & 15, lk = lane >> 4;
        int row0 = bid * 16;

        f32x4 acc[16];
#pragma unroll
        for (int j = 0; j < 16; ++j) acc[j] = (f32x4){0.f, 0.f, 0.f, 0.f};

        const short* A = (const short*)qb + (long long)(row0 + la) * Dn;
        const short* Bp = (const short*)pbuf;
#pragma unroll
        for (int kc = 0; kc < Dn; kc += 32) {
            short8v a = *(const short8v*)(A + kc + lk * 8);
#pragma unroll
            for (int j = 0; j < 16; ++j) {
                int prow = w * 256 + j * 16 + la;
                short8v b = *(const short8v*)(Bp + (long long)prow * Dn + kc + lk * 8);
                acc[j] = __builtin_amdgcn_mfma_f32_16x16x32_bf16(a, b, acc[j], 0, 0, 0);
            }
        }

        float m[4];
#pragma unroll
        for (int rg = 0; rg < 4; ++rg) {
            float v = -INFINITY;
#pragma unroll
            for (int j = 0; j < 16; ++j) {
                int col = w * 256 + j * 16 + la;
                if (col < Cn) v = fmaxf(v, acc[j][rg]);
            }
#pragma unroll
            for (int o = 1; o < 16; o <<= 1) v = fmaxf(v, __shfl_xor(v, o));
            m[rg] = v;
        }
        if (la == 0) {
#pragma unroll
            for (int rg = 0; rg < 4; ++rg) red[lk * 4 + rg][w] = m[rg];
        }
        __syncthreads();
#pragma unroll
        for (int rg = 0; rg < 4; ++rg) {
            int r = lk * 4 + rg;
            m[rg] = fmaxf(fmaxf(red[r][0], red[r][1]), fmaxf(red[r][2], red[r][3]));
        }
        __syncthreads();

        float s[4];
#pragma unroll
        for (int rg = 0; rg < 4; ++rg) {
            float v = 0.f;
#pragma unroll
            for (int j = 0; j < 16; ++j) {
                int col = w * 256 + j * 16 + la;
                float e = (col < Cn) ? expf(acc[j][rg] - m[rg]) : 0.f;
                acc[j][rg] = e;
                v += e;
            }
#pragma unroll
            for (int o = 1; o < 16; o <<= 1) v += __shfl_xor(v, o);
            s[rg] = v;
        }
        if (la == 0) {
#pragma unroll
            for (int rg = 0; rg < 4; ++rg) red[lk * 4 + rg][w] = s[rg];
        }
        __syncthreads();
#pragma unroll
        for (int rg = 0; rg < 4; ++rg) {
            int r = lk * 4 + rg;
            s[rg] = 1.f / (red[r][0] + red[r][1] + red[r][2] + red[r][3]);
        }

#pragma unroll
        for (int j = 0; j < 16; ++j) {
            int col = w * 256 + j * 16 + la;
            if (col < Cn) {
                int rowb = row0 + lk * 4;
#pragma unroll
                for (int rg = 0; rg < 4; ++rg)
                    __builtin_nontemporal_store(acc[j][rg] * s[rg],
                        outC + (long long)(rowb + rg) * Cn + col);
            }
        }
    } else if (bid < 756) {
        // ---- prototype EMA + L2 norm, 2 classes/block, ushort-staged (16.4 KB) ----
        u16* slab = (u16*)smem;                        // [4096]  8 KB
        u16* list0 = (u16*)(smem + 8192);              // [2048]  4 KB
        u16* list1 = (u16*)(smem + 12288);             // [2048]  4 KB
        int* nm = (int*)(smem + 16384);                // [2]
        float* shh = (float*)(smem + 16392);           // [4]

        int h = t >> 7, tt = t & 127;
        int c = (bid - 256) * 2 + h;                   // < 1000 always

#pragma unroll
        for (int u = 0; u < 4; ++u) {
            int4 v = ((const int4*)lbl)[u * 256 + t];
            int base = (u * 256 + t) * 4;
            slab[base + 0] = (u16)v.x; slab[base + 1] = (u16)v.y;
            slab[base + 2] = (u16)v.z; slab[base + 3] = (u16)v.w;
        }
        if (t == 0)   nm[0] = 0;
        if (t == 128) nm[1] = 0;
        __syncthreads();

        int wv = t >> 6;
        if ((wv & 1) == 0) {            // waves 0 and 2 scan for their half's class
            int hh = wv >> 1;
            int ln = t & 63;
            u16 cc = (u16)((bid - 256) * 2 + hh);
            u16* lst = hh ? list1 : list0;
            int n = 0;
            for (int jj = 0; jj < Bn / 64; ++jj) {
                unsigned long long mask = __ballot(slab[jj * 64 + ln] == cc);
                if (ln == 0) {
                    while (mask && n < 2048) {
                        int b = __builtin_ctzll(mask);
                        lst[n++] = (u16)(jj * 64 + b);
                        mask &= mask - 1;
                    }
                }
            }
            if (ln == 0) nm[hh] = n;
        }
        __syncthreads();

        int n = nm[h];
        u16* lst = h ? list1 : list0;
        float acc = proto[(long long)c * Dn + tt];
        for (int mi = 0; mi < n; ++mi)
            acc = 0.99f * acc + 0.01f * q[(long long)lst[mi] * Dn + tt];

        float ss = waveSumF(acc * acc);
        if ((t & 63) == 0) shh[t >> 6] = ss;
        __syncthreads();
        float nn = sqrtf(shh[h * 2] + shh[h * 2 + 1]);
        outp[(long long)c * Dn + tt] = acc / fmaxf(nn, 1e-12f);
    } else if (bid < 1301) {
        // ---- labels / queue_pseudo / ptr tail (545 blocks) ----
        int gid = (bid - 756) * 256 + t;
        const int NL = 2 * Bn + Qn;   // 73728
        int p = *ptrp;
        int pc = p < 0 ? 0 : (p > Qn - Bn ? Qn - Bn : p);
        if (gid < NL) {
            float v;
            if (gid < Bn)          v = (float)lbl[gid];
            else if (gid < 2 * Bn) v = (float)lbl[gid - Bn];
            else                   v = qps[gid - 2 * Bn];
            out_lab[gid] = v;
        }
        int j = gid - NL;
        if (j >= 0 && j < Qn) {
            unsigned rr = (unsigned)(j - pc);
            out_qps[j] = (rr < (unsigned)Bn) ? (float)lbl[rr] : qps[j];
        }
        if (gid == NL + Qn) out_ptr[0] = (float)((p + Bn) % Qn);
    } else if (bid < 1557) {
        // ---- feat q|k tile: 4096 floats, entirely one source (MLP-4, NT) ----
        int fb = bid - 1301;
        const float* src = (fb < 128) ? q : kk;
        long long sb = (long long)(fb & 127) * 4096;
        long long db = (long long)fb * 4096;
        f4v v[4];
#pragma unroll
        for (int u = 0; u < 4; ++u)
            v[u] = *(const f4v*)(src + sb + (u * 256 + t) * 4);
#pragma unroll
        for (int u = 0; u < 4; ++u)
            nts(v[u], (f4v*)(out_feat + db + (u * 256 + t) * 4));
    } else {
        // ---- queue tile: 4096 floats; all loads first, then stores (NT) ----
        int cb = bid - 1557;
        int p = *ptrp;
        int pc = p < 0 ? 0 : (p > Qn - Bn ? Qn - Bn : p);
        long long base = (long long)cb * 4096;
        const long long FB = 2LL * Bn * Dn;      // 1048576
        f4v v[4];
#pragma unroll
        for (int u = 0; u < 4; ++u)
            v[u] = ntl((const f4v*)(queue + base + (u * 256 + t) * 4));
#pragma unroll
        for (int u = 0; u < 4; ++u)
            nts(v[u], (f4v*)(out_feat + FB + base + (u * 256 + t) * 4));
#pragma unroll
        for (int u = 0; u < 4; ++u) {
            long long foff = base + (u * 256 + t) * 4;
            int row = (int)(foff >> 7);
            unsigned rr = (unsigned)(row - pc);
            f4v wv = v[u];
            if (rr < (unsigned)Bn) wv = *(const f4v*)(kk + (long long)rr * Dn + (foff & 127));
            nts(wv, (f4v*)(out_queue + foff));
        }
    }
}

// ---------------- host ----------------
extern "C" void kernel_launch(void* const* d_in, const int* in_sizes, int n_in,
                              void* d_out, int out_size, void* d_ws, size_t ws_size,
                              hipStream_t stream)
{
    const float* q     = (const float*)d_in[0];
    const float* kk    = (const float*)d_in[1];
    const float* cl    = (const float*)d_in[2];
    const float* plab  = (const float*)d_in[3];
    const float* proto = (const float*)d_in[4];
    const float* queue = (const float*)d_in[5];
    const float* qps   = (const float*)d_in[6];
    const int*   ptrp  = (const int*)d_in[7];

    float* out = (float*)d_out;
    // output layout (flat float offsets, return order)
    const long long O_CLU  = 4096000;     // cluster_out
    const long long O_FEAT = 8192000;     // cont_features
    const long long O_LAB  = 17629184;    // cont_labels
    const long long O_PROT = 17702912;    // new_prototypes
    const long long O_QUE  = 17830912;    // new_queue
    const long long O_QPS  = 26219520;    // new_queue_pseudo
    const long long O_PTR  = 26285056;    // new_ptr

    char* ws = (char*)d_ws;
    int*   lbl = (int*)(ws + 0);                           // [4096]
    __hip_bfloat16* qb = (__hip_bfloat16*)(ws + 1048576);  // [4096*128] bf16
    __hip_bfloat16* pb = (__hip_bfloat16*)(ws + 2097152);  // [1024*128] bf16 (padded)

    k_cls<<<1024, 256, 0, stream>>>(cl, plab, q, proto, out, lbl, qb, pb);
    k_rest<<<3605, 256, 0, stream>>>(qb, pb, proto, q, kk, queue, lbl, qps, ptrp,
                                     out + O_CLU, out + O_PROT,
                                     out + O_LAB, out + O_QPS, out + O_PTR,
                                     out + O_FEAT, out + O_QUE);
}